// Round 3
// baseline (34.414 us; speedup 1.0000x reference)
//
#include <hip/hip_runtime.h>

// Gaussian cross-attention: out[b,m,:] = sum_k w[b,m,k] * Q[b,k,:]
// Write-BW-bound (134 MB out). Key opt: register-stage Q[b] fragments per
// thread (5 x float4 = 20 VGPR) and amortize over ROWS rows per block,
// cutting L2 Q re-read traffic 16x vs one-row-per-block.

#define K_SUP 5
#define ROWS  16   // rows per block; block covers full D with 256 threads

typedef float f32x4 __attribute__((ext_vector_type(4)));

__global__ __launch_bounds__(256)
void gauss_xattn_kernel(const int* __restrict__ seg,
                        const float* __restrict__ Q,
                        float* __restrict__ out,
                        int M, int D) {
    const int groups_per_b = M / ROWS;            // 32
    const int g  = blockIdx.x;
    const int b  = g / groups_per_b;
    const int m0 = (g % groups_per_b) * ROWS;
    const int n  = seg[b];
    const int d  = threadIdx.x * 4;               // 256 threads x float4 == D=1024

    // Register-stage the 5 Q fragments for this thread's d-slice.
    f32x4 q[K_SUP];
    const bool need_q = (m0 < n) || (n == 1 && m0 == 0);
    if (need_q) {
        const float* __restrict__ Qb = Q + ((size_t)b * K_SUP) * D + d;
        #pragma unroll
        for (int k = 0; k < K_SUP; ++k)
            q[k] = *reinterpret_cast<const f32x4*>(Qb + (size_t)k * D);
    }

    float* __restrict__ orow = out + ((size_t)(b * M + m0)) * D + d;

    #pragma unroll
    for (int r = 0; r < ROWS; ++r, orow += D) {
        const int m = m0 + r;
        f32x4 o = (f32x4)(0.0f);

        if (n == 1) {
            if (m == 0) {
                // all-ones weight row: out = sum_k Q[b][k][:]
                #pragma unroll
                for (int k = 0; k < K_SUP; ++k) o += q[k];
            }
        } else if (m < n) {
            const float mu = (float)m * 4.0f / (float)(n - 1);
            float l[K_SUP];
            #pragma unroll
            for (int k = 0; k < K_SUP; ++k) {
                const float z = ((float)k - mu) * (1.0f / 2.5f);
                l[k] = __expf(-0.5f * z * z);
            }
            const float lmin = fminf(fminf(fminf(l[0], l[1]), fminf(l[2], l[3])), l[4]);
            const float lmax = fmaxf(fmaxf(fmaxf(l[0], l[1]), fmaxf(l[2], l[3])), l[4]);
            const float inv = 1.0f / (lmax - lmin);
            #pragma unroll
            for (int k = 0; k < K_SUP; ++k) {
                const float wk = (l[k] - lmin) * inv;
                o += wk * q[k];
            }
        }
        // rows >= n fall through with zeros (output is poisoned, must write)

        __builtin_nontemporal_store(o, reinterpret_cast<f32x4*>(orow));
    }
}

extern "C" void kernel_launch(void* const* d_in, const int* in_sizes, int n_in,
                              void* d_out, int out_size, void* d_ws, size_t ws_size,
                              hipStream_t stream) {
    const int*   seg = (const int*)d_in[0];
    const float* Q   = (const float*)d_in[2];
    float*       out = (float*)d_out;

    const int B = in_sizes[0];
    const int D = in_sizes[2] / (B * K_SUP);   // 1024
    const int M = out_size / (B * D);          // 512

    dim3 grid(B * (M / ROWS));                 // 64 * 32 = 2048 blocks
    gauss_xattn_kernel<<<grid, 256, 0, stream>>>(seg, Q, out, M, D);
}

// Round 4
// 28.050 us; speedup vs baseline: 1.2269x; 1.2269x over previous
//
#include <hip/hip_runtime.h>

// Gaussian cross-attention: out[b,m,:] = sum_k w[b,m,k] * Q[b,k,:]
// Write-BW-bound (134 MB out). Register-stage Q[b] fragments per thread
// (5 x float4 = 20 VGPR), amortize over ROWS rows per block (16x fewer L2
// Q re-reads vs one-row-per-block). Plain cache-path stores: the nt flag
// (R3) bypassed L2/L3 write absorption and regressed 29.8 -> 34.4 us.

#define K_SUP 5
#define ROWS  16   // rows per block; block covers full D with 256 threads

typedef float f32x4 __attribute__((ext_vector_type(4)));

__global__ __launch_bounds__(256)
void gauss_xattn_kernel(const int* __restrict__ seg,
                        const float* __restrict__ Q,
                        float* __restrict__ out,
                        int M, int D) {
    const int groups_per_b = M / ROWS;            // 32
    const int g  = blockIdx.x;
    const int b  = g / groups_per_b;
    const int m0 = (g % groups_per_b) * ROWS;
    const int n  = seg[b];
    const int d  = threadIdx.x * 4;               // 256 threads x float4 == D=1024

    // Register-stage the 5 Q fragments for this thread's d-slice.
    f32x4 q[K_SUP];
    const bool need_q = (m0 < n) || (n == 1 && m0 == 0);
    if (need_q) {
        const float* __restrict__ Qb = Q + ((size_t)b * K_SUP) * D + d;
        #pragma unroll
        for (int k = 0; k < K_SUP; ++k)
            q[k] = *reinterpret_cast<const f32x4*>(Qb + (size_t)k * D);
    }

    float* __restrict__ orow = out + ((size_t)(b * M + m0)) * D + d;

    #pragma unroll
    for (int r = 0; r < ROWS; ++r, orow += D) {
        const int m = m0 + r;
        f32x4 o = (f32x4)(0.0f);

        if (n == 1) {
            if (m == 0) {
                // all-ones weight row: out = sum_k Q[b][k][:]
                #pragma unroll
                for (int k = 0; k < K_SUP; ++k) o += q[k];
            }
        } else if (m < n) {
            const float mu = (float)m * 4.0f / (float)(n - 1);
            float l[K_SUP];
            #pragma unroll
            for (int k = 0; k < K_SUP; ++k) {
                const float z = ((float)k - mu) * (1.0f / 2.5f);
                l[k] = __expf(-0.5f * z * z);
            }
            const float lmin = fminf(fminf(fminf(l[0], l[1]), fminf(l[2], l[3])), l[4]);
            const float lmax = fmaxf(fmaxf(fmaxf(l[0], l[1]), fmaxf(l[2], l[3])), l[4]);
            const float inv = 1.0f / (lmax - lmin);
            #pragma unroll
            for (int k = 0; k < K_SUP; ++k) {
                const float wk = (l[k] - lmin) * inv;
                o += wk * q[k];
            }
        }
        // rows >= n fall through with zeros (output is poisoned, must write)

        *reinterpret_cast<f32x4*>(orow) = o;
    }
}

extern "C" void kernel_launch(void* const* d_in, const int* in_sizes, int n_in,
                              void* d_out, int out_size, void* d_ws, size_t ws_size,
                              hipStream_t stream) {
    const int*   seg = (const int*)d_in[0];
    const float* Q   = (const float*)d_in[2];
    float*       out = (float*)d_out;

    const int B = in_sizes[0];
    const int D = in_sizes[2] / (B * K_SUP);   // 1024
    const int M = out_size / (B * D);          // 512

    dim3 grid(B * (M / ROWS));                 // 64 * 32 = 2048 blocks
    gauss_xattn_kernel<<<grid, 256, 0, stream>>>(seg, Q, out, M, D);
}

// Round 5
// 25.836 us; speedup vs baseline: 1.3320x; 1.0857x over previous
//
#include <hip/hip_runtime.h>

// Gaussian cross-attention: out[b,m,:] = sum_k w[b,m,k] * Q[b,k,:]
// Write-BW-bound (134 MB out; floor ~19.6 us @ 6.85 TB/s fill ceiling).
// R4 gap analysis: per-row weight math (5x exp + minmax, ~150 cyc/wave/row)
// redundantly done by all threads ~= 8 us of VALU issue. Fix: 16 threads
// precompute the block's 16x5 weights into LDS once; row loop is branchless
// {2 broadcast ds_reads, 20 FMA, 1 float4 store}.

#define K_SUP 5
#define ROWS  16   // rows per block; 256 threads x float4 covers D=1024

typedef float f32x4 __attribute__((ext_vector_type(4)));

__global__ __launch_bounds__(256)
void gauss_xattn_kernel(const int* __restrict__ seg,
                        const float* __restrict__ Q,
                        float* __restrict__ out,
                        int M, int D) {
    const int groups_per_b = M / ROWS;            // 32
    const int g   = blockIdx.x;
    const int b   = g / groups_per_b;
    const int m0  = (g % groups_per_b) * ROWS;
    const int n   = seg[b];
    const int tid = threadIdx.x;
    const int d   = tid * 4;

    __shared__ float wsh[ROWS][8];                // padded to 8 for b128+b32 reads

    // --- prologue: 16 threads compute per-row weights (incl. all edge cases)
    if (tid < ROWS) {
        const int m = m0 + tid;
        float w[K_SUP];
        if (n == 1) {
            const float v = (m == 0) ? 1.0f : 0.0f;
            #pragma unroll
            for (int k = 0; k < K_SUP; ++k) w[k] = v;
        } else if (m < n) {
            const float mu = (float)m * 4.0f / (float)(n - 1);
            float l[K_SUP];
            #pragma unroll
            for (int k = 0; k < K_SUP; ++k) {
                const float z = ((float)k - mu) * (1.0f / 2.5f);
                l[k] = __expf(-0.5f * z * z);
            }
            const float lmin = fminf(fminf(fminf(l[0], l[1]), fminf(l[2], l[3])), l[4]);
            const float lmax = fmaxf(fmaxf(fmaxf(l[0], l[1]), fmaxf(l[2], l[3])), l[4]);
            const float inv = 1.0f / (lmax - lmin);
            #pragma unroll
            for (int k = 0; k < K_SUP; ++k) w[k] = (l[k] - lmin) * inv;
        } else {
            #pragma unroll
            for (int k = 0; k < K_SUP; ++k) w[k] = 0.0f;
        }
        #pragma unroll
        for (int k = 0; k < K_SUP; ++k) wsh[tid][k] = w[k];
    }

    // --- register-stage the 5 Q fragments for this thread's d-slice
    f32x4 q[K_SUP];
    const float* __restrict__ Qb = Q + ((size_t)b * K_SUP) * D + d;
    #pragma unroll
    for (int k = 0; k < K_SUP; ++k)
        q[k] = *reinterpret_cast<const f32x4*>(Qb + (size_t)k * D);

    __syncthreads();

    float* __restrict__ orow = out + ((size_t)(b * M + m0)) * D + d;

    // --- branchless row loop: broadcast weights, 20 FMA, 1 store
    #pragma unroll
    for (int r = 0; r < ROWS; ++r, orow += D) {
        const f32x4 w4 = *reinterpret_cast<const f32x4*>(&wsh[r][0]); // broadcast
        const float w5 = wsh[r][4];
        f32x4 o = w4.x * q[0];
        o += w4.y * q[1];
        o += w4.z * q[2];
        o += w4.w * q[3];
        o += w5   * q[4];
        *reinterpret_cast<f32x4*>(orow) = o;
    }
}

extern "C" void kernel_launch(void* const* d_in, const int* in_sizes, int n_in,
                              void* d_out, int out_size, void* d_ws, size_t ws_size,
                              hipStream_t stream) {
    const int*   seg = (const int*)d_in[0];
    const float* Q   = (const float*)d_in[2];
    float*       out = (float*)d_out;

    const int B = in_sizes[0];
    const int D = in_sizes[2] / (B * K_SUP);   // 1024
    const int M = out_size / (B * D);          // 512

    dim3 grid(B * (M / ROWS));                 // 64 * 32 = 2048 blocks
    gauss_xattn_kernel<<<grid, 256, 0, stream>>>(seg, Q, out, M, D);
}

// Round 6
// 25.443 us; speedup vs baseline: 1.3526x; 1.0154x over previous
//
#include <hip/hip_runtime.h>

// Gaussian cross-attention: out[b,m,:] = sum_k w[b,m,k] * Q[b,k,:]
// Write-BW-bound (134 MB out; fill ceiling ~6.85 TB/s -> 19.6 us floor).
// R5 = 25.8 us. Residual is prologue/barrier/tail overhead, not issue rate:
//  - ROWS=32 halves block count (1024) -> half the prologues/barriers/tails
//  - Q loads issued BEFORE the exp chain so they fly under it
//  - LDS broadcast of per-row weights; branchless {2 ds_read, 20 FMA, 1 store}

#define K_SUP 5
#define ROWS  32   // rows per block; 256 threads x float4 covers D=1024

typedef float f32x4 __attribute__((ext_vector_type(4)));

__global__ __launch_bounds__(256)
void gauss_xattn_kernel(const int* __restrict__ seg,
                        const float* __restrict__ Q,
                        float* __restrict__ out,
                        int M, int D) {
    const int groups_per_b = M / ROWS;            // 16
    const int g   = blockIdx.x;
    const int b   = g / groups_per_b;
    const int m0  = (g % groups_per_b) * ROWS;
    const int tid = threadIdx.x;
    const int d   = tid * 4;

    __shared__ float wsh[ROWS][8];                // padded: b128 + b32 reads

    // --- issue Q loads first so they overlap the weight computation
    f32x4 q[K_SUP];
    const float* __restrict__ Qb = Q + ((size_t)b * K_SUP) * D + d;
    #pragma unroll
    for (int k = 0; k < K_SUP; ++k)
        q[k] = *reinterpret_cast<const f32x4*>(Qb + (size_t)k * D);

    const int n = seg[b];

    // --- 32 lanes compute per-row weights (incl. all edge cases)
    if (tid < ROWS) {
        const int m = m0 + tid;
        float w[K_SUP];
        if (n == 1) {
            const float v = (m == 0) ? 1.0f : 0.0f;
            #pragma unroll
            for (int k = 0; k < K_SUP; ++k) w[k] = v;
        } else if (m < n) {
            const float mu = (float)m * 4.0f / (float)(n - 1);
            float l[K_SUP];
            #pragma unroll
            for (int k = 0; k < K_SUP; ++k) {
                const float z = ((float)k - mu) * (1.0f / 2.5f);
                l[k] = __expf(-0.5f * z * z);
            }
            const float lmin = fminf(fminf(fminf(l[0], l[1]), fminf(l[2], l[3])), l[4]);
            const float lmax = fmaxf(fmaxf(fmaxf(l[0], l[1]), fmaxf(l[2], l[3])), l[4]);
            const float inv = 1.0f / (lmax - lmin);
            #pragma unroll
            for (int k = 0; k < K_SUP; ++k) w[k] = (l[k] - lmin) * inv;
        } else {
            #pragma unroll
            for (int k = 0; k < K_SUP; ++k) w[k] = 0.0f;
        }
        #pragma unroll
        for (int k = 0; k < K_SUP; ++k) wsh[tid][k] = w[k];
    }

    __syncthreads();

    float* __restrict__ orow = out + ((size_t)(b * M + m0)) * D + d;

    // --- branchless row loop: broadcast weights, 20 FMA, 1 store
    #pragma unroll
    for (int r = 0; r < ROWS; ++r, orow += D) {
        const f32x4 w4 = *reinterpret_cast<const f32x4*>(&wsh[r][0]); // broadcast
        const float w5 = wsh[r][4];
        f32x4 o = w4.x * q[0];
        o += w4.y * q[1];
        o += w4.z * q[2];
        o += w4.w * q[3];
        o += w5   * q[4];
        *reinterpret_cast<f32x4*>(orow) = o;
    }
}

extern "C" void kernel_launch(void* const* d_in, const int* in_sizes, int n_in,
                              void* d_out, int out_size, void* d_ws, size_t ws_size,
                              hipStream_t stream) {
    const int*   seg = (const int*)d_in[0];
    const float* Q   = (const float*)d_in[2];
    float*       out = (float*)d_out;

    const int B = in_sizes[0];
    const int D = in_sizes[2] / (B * K_SUP);   // 1024
    const int M = out_size / (B * D);          // 512

    dim3 grid(B * (M / ROWS));                 // 64 * 16 = 1024 blocks
    gauss_xattn_kernel<<<grid, 256, 0, stream>>>(seg, Q, out, M, D);
}